// Round 7
// baseline (79.937 us; speedup 1.0000x reference)
//
#include <hip/hip_runtime.h>

#define NB 8
#define TS 16
#define PR 20   // product region (tile + 2 halo each side)
#define GR 22   // g1 region (tile + 3 halo each side)
#define SW 24   // padded LDS row stride
#define SFW 12  // coarse-flow staging window (covers any 20px target span)
#define GW 28   // G2 warp window: [t0-5, t0+22] covers |flow|<=3 beyond halo
#define GWS 29  // G2 window row stride

typedef float f2 __attribute__((ext_vector_type(2)));

// Fused: channel-mean gray of both 512x512 images + 2x2 avg-pool to level 1.
__global__ void gray_pool_kernel(const float* __restrict__ img1, const float* __restrict__ img2,
                                 float* __restrict__ g0a, float* __restrict__ g0b,
                                 float* __restrict__ g1a, float* __restrict__ g1b) {
    const int W = 512, HW = 512 * 512, Wq = 256, HWq = 256 * 256;
    int i = blockIdx.x * blockDim.x + threadIdx.x;
    if (i >= NB * HWq) return;
    int qx = i % Wq;
    int qy = (i / Wq) % Wq;
    int b = i / HWq;
    size_t base = (size_t)b * 3 * HW + (size_t)(2 * qy) * W + 2 * qx;
    const float third = 1.0f / 3.0f;

    f2 a0c0 = __builtin_nontemporal_load((const f2*)(img1 + base));
    f2 a1c0 = __builtin_nontemporal_load((const f2*)(img1 + base + W));
    f2 a0c1 = __builtin_nontemporal_load((const f2*)(img1 + base + HW));
    f2 a1c1 = __builtin_nontemporal_load((const f2*)(img1 + base + HW + W));
    f2 a0c2 = __builtin_nontemporal_load((const f2*)(img1 + base + 2 * HW));
    f2 a1c2 = __builtin_nontemporal_load((const f2*)(img1 + base + 2 * HW + W));
    float p00 = (a0c0.x + a0c1.x + a0c2.x) * third;
    float p01 = (a0c0.y + a0c1.y + a0c2.y) * third;
    float p10 = (a1c0.x + a1c1.x + a1c2.x) * third;
    float p11 = (a1c0.y + a1c1.y + a1c2.y) * third;
    size_t gbase = (size_t)b * HW + (size_t)(2 * qy) * W + 2 * qx;
    *(f2*)(g0a + gbase) = (f2){p00, p01};
    *(f2*)(g0a + gbase + W) = (f2){p10, p11};
    g1a[(size_t)b * HWq + qy * Wq + qx] = (p00 + p01 + p10 + p11) * 0.25f;

    f2 b0c0 = __builtin_nontemporal_load((const f2*)(img2 + base));
    f2 b1c0 = __builtin_nontemporal_load((const f2*)(img2 + base + W));
    f2 b0c1 = __builtin_nontemporal_load((const f2*)(img2 + base + HW));
    f2 b1c1 = __builtin_nontemporal_load((const f2*)(img2 + base + HW + W));
    f2 b0c2 = __builtin_nontemporal_load((const f2*)(img2 + base + 2 * HW));
    f2 b1c2 = __builtin_nontemporal_load((const f2*)(img2 + base + 2 * HW + W));
    float q00 = (b0c0.x + b0c1.x + b0c2.x) * third;
    float q01 = (b0c0.y + b0c1.y + b0c2.y) * third;
    float q10 = (b1c0.x + b1c1.x + b1c2.x) * third;
    float q11 = (b1c0.y + b1c1.y + b1c2.y) * third;
    *(f2*)(g0b + gbase) = (f2){q00, q01};
    *(f2*)(g0b + gbase + W) = (f2){q10, q11};
    g1b[(size_t)b * HWq + qy * Wq + qx] = (q00 + q01 + q10 + q11) * 0.25f;
}

// Fused pyramid levels 2+3 for both images.
__global__ void down2_kernel(const float* __restrict__ l1a, const float* __restrict__ l1b,
                             float* __restrict__ l2a, float* __restrict__ l2b,
                             float* __restrict__ l3a, float* __restrict__ l3b) {
    const int W3 = 64, W2 = 128, W1 = 256;
    int i = blockIdx.x * blockDim.x + threadIdx.x;
    int total = 2 * NB * W3 * W3;
    if (i >= total) return;
    int x3 = i % W3;
    int y3 = (i / W3) % W3;
    int b = (i / (W3 * W3)) % NB;
    int j = i / (NB * W3 * W3);
    const float* l1 = (j ? l1b : l1a) + (size_t)b * W1 * W1;
    float* l2 = (j ? l2b : l2a) + (size_t)b * W2 * W2;
    float* l3 = (j ? l3b : l3a) + (size_t)b * W3 * W3;
    float4 r0 = *(const float4*)(l1 + (size_t)(4 * y3 + 0) * W1 + 4 * x3);
    float4 r1 = *(const float4*)(l1 + (size_t)(4 * y3 + 1) * W1 + 4 * x3);
    float4 r2 = *(const float4*)(l1 + (size_t)(4 * y3 + 2) * W1 + 4 * x3);
    float4 r3 = *(const float4*)(l1 + (size_t)(4 * y3 + 3) * W1 + 4 * x3);
    float a00 = (r0.x + r0.y + r1.x + r1.y) * 0.25f;
    float a01 = (r0.z + r0.w + r1.z + r1.w) * 0.25f;
    float a10 = (r2.x + r2.y + r3.x + r3.y) * 0.25f;
    float a11 = (r2.z + r2.w + r3.z + r3.w) * 0.25f;
    *(f2*)(l2 + (size_t)(2 * y3) * W2 + 2 * x3) = (f2){a00, a01};
    *(f2*)(l2 + (size_t)(2 * y3 + 1) * W2 + 2 * x3) = (f2){a10, a11};
    l3[y3 * W3 + x3] = (a00 + a01 + a10 + a11) * 0.25f;
}

// 16x16-tile LK. G1 tile, G2 warp-window, and coarse flow all staged in LDS;
// branch-free bilinear warp from LDS (global fallback for |flow|>3).
template <int MODE>
__global__ __launch_bounds__(256) void lk_kernel(
    const float* __restrict__ g1, const float* __restrict__ g2,
    const float* __restrict__ fin, float* __restrict__ fout, int H, int W) {
    __shared__ float sG[GR][SW];
    __shared__ float sG2[GW][GWS];
    __shared__ float sP[5][PR][SW];
    __shared__ float sH[5][PR][16];
    __shared__ float sFU[SFW][SFW + 1], sFV[SFW][SFW + 1];

    int nbx = W / TS;
    int b = blockIdx.x % NB;
    int t = blockIdx.x / NB;
    int ty0 = (t / nbx) * TS, tx0 = (t % nbx) * TS;
    int tid = threadIdx.x;
    int lx = tid % TS, ly = tid / TS;

    const float* G1 = g1 + (size_t)b * H * W;
    const float* G2 = g2 + (size_t)b * H * W;
    bool interior = (ty0 >= 3) && (ty0 + TS + 3 <= H) && (tx0 >= 3) && (tx0 + TS + 3 <= W);

    int Hs = H >> 1, Ws = W >> 1;
    float scale = (float)(Hs - 1) / (float)(H - 1);
    int yA = 0, xA = 0;
    if (MODE == 1) {
        yA = min(max((int)((float)max(ty0 - 2, 0) * scale), 0), Hs - 2);
        xA = min(max((int)((float)max(tx0 - 2, 0) * scale), 0), Ws - 2);
        const float* FU = fin + (size_t)b * 2 * Hs * Ws;
        const float* FV = FU + Hs * Ws;
        for (int i = tid; i < 2 * SFW * SFW; i += 256) {
            int ch = i / (SFW * SFW);
            int rem = i % (SFW * SFW);
            int r = rem / SFW, c = rem % SFW;
            int ys = min(yA + r, Hs - 1), xs = min(xA + c, Ws - 1);
            float v = (ch ? FV : FU)[(size_t)ys * Ws + xs];
            if (ch) sFV[r][c] = v; else sFU[r][c] = v;
        }
    }
    // stage G1 tile (halo 3, zero-padded)
    if (interior) {
        for (int i = tid; i < GR * GR; i += 256) {
            int r = i / GR, c = i % GR;
            sG[r][c] = G1[(ty0 - 3 + r) * W + (tx0 - 3 + c)];
        }
    } else {
        for (int i = tid; i < GR * GR; i += 256) {
            int r = i / GR, c = i % GR;
            int gy = ty0 - 3 + r, gx = tx0 - 3 + c;
            float v = 0.0f;
            if (gy >= 0 && gy < H && gx >= 0 && gx < W) v = G1[gy * W + gx];
            sG[r][c] = v;
        }
    }
    // stage G2 warp window [t0-5, t0+22]^2 (zero-padded; masks zero invalid corners)
    {
        bool winin = (ty0 >= 5) && (ty0 + 23 <= H) && (tx0 >= 5) && (tx0 + 23 <= W);
        if (winin) {
            for (int i = tid; i < GW * GW; i += 256) {
                int r = i / GW, c = i % GW;
                sG2[r][c] = G2[(ty0 - 5 + r) * W + (tx0 - 5 + c)];
            }
        } else {
            for (int i = tid; i < GW * GW; i += 256) {
                int r = i / GW, c = i % GW;
                int gy = ty0 - 5 + r, gx = tx0 - 5 + c;
                float v = 0.0f;
                if (gy >= 0 && gy < H && gx >= 0 && gx < W) v = G2[gy * W + gx];
                sG2[r][c] = v;
            }
        }
    }
    __syncthreads();

    // phase 2: flow interp + Sobel + LDS bilinear warp + products (20x20 region)
#pragma unroll
    for (int it = 0; it < 2; ++it) {
        int i = tid + it * 256;
        if (i < PR * PR) {
            int r = i / PR, c = i % PR;
            int gy = ty0 - 2 + r, gx = tx0 - 2 + c;
            float su = 0.0f, sv = 0.0f;
            if (MODE == 1) {
                float sy = (float)gy * scale, sx = (float)gx * scale;
                int y0 = min(max((int)sy, 0), Hs - 2);
                int x0 = min(max((int)sx, 0), Ws - 2);
                float wyf = sy - (float)y0, wxf = sx - (float)x0;
                int ry = y0 - yA, rx = x0 - xA;
                float ut = sFU[ry][rx] * (1.0f - wyf) + sFU[ry + 1][rx] * wyf;
                float ub = sFU[ry][rx + 1] * (1.0f - wyf) + sFU[ry + 1][rx + 1] * wyf;
                float vt = sFV[ry][rx] * (1.0f - wyf) + sFV[ry + 1][rx] * wyf;
                float vb = sFV[ry][rx + 1] * (1.0f - wyf) + sFV[ry + 1][rx + 1] * wyf;
                su = 2.0f * (ut * (1.0f - wxf) + ub * wxf);
                sv = 2.0f * (vt * (1.0f - wxf) + vb * wxf);
            }
            float xx = (float)gx + su, yy = (float)gy + sv;
            float x0f = floorf(xx), y0f = floorf(yy);
            float wx = xx - x0f, wy = yy - y0f;
            float Wm1 = (float)(W - 1), Hm1 = (float)(H - 1);
            float mx0 = (x0f >= 0.0f && x0f <= Wm1) ? 1.0f : 0.0f;
            float mx1 = (x0f + 1.0f >= 0.0f && x0f + 1.0f <= Wm1) ? 1.0f : 0.0f;
            float my0 = (y0f >= 0.0f && y0f <= Hm1) ? 1.0f : 0.0f;
            float my1 = (y0f + 1.0f >= 0.0f && y0f + 1.0f <= Hm1) ? 1.0f : 0.0f;
            float w00 = (1.0f - wx) * (1.0f - wy) * mx0 * my0;
            float w01 = wx * (1.0f - wy) * mx1 * my0;
            float w10 = (1.0f - wx) * wy * mx0 * my1;
            float w11 = wx * wy * mx1 * my1;
            // in-window test against [t0-5, t0+21] (so +1 corner stays <= t0+22)
            bool inwin = (y0f >= (float)(ty0 - 5)) && (y0f <= (float)(ty0 + 21))
                      && (x0f >= (float)(tx0 - 5)) && (x0f <= (float)(tx0 + 21));
            float I2w;
            if (__builtin_expect(inwin, 1)) {
                int ry = (int)y0f - (ty0 - 5);
                int rx = (int)x0f - (tx0 - 5);
                I2w = sG2[ry][rx] * w00 + sG2[ry][rx + 1] * w01
                    + sG2[ry + 1][rx] * w10 + sG2[ry + 1][rx + 1] * w11;
            } else {
                int xi = (int)x0f, yi = (int)y0f;
                int xc0 = min(max(xi, 0), W - 1), xc1 = min(max(xi + 1, 0), W - 1);
                int yc0 = min(max(yi, 0), H - 1), yc1 = min(max(yi + 1, 0), H - 1);
                I2w = G2[yc0 * W + xc0] * w00 + G2[yc0 * W + xc1] * w01
                    + G2[yc1 * W + xc0] * w10 + G2[yc1 * W + xc1] * w11;
            }
            float Ix = (-sG[r][c] + sG[r][c + 2]
                        - 2.0f * sG[r + 1][c] + 2.0f * sG[r + 1][c + 2]
                        - sG[r + 2][c] + sG[r + 2][c + 2]) * 0.125f;
            float Iy = (-sG[r][c] - 2.0f * sG[r][c + 1] - sG[r][c + 2]
                        + sG[r + 2][c] + 2.0f * sG[r + 2][c + 1] + sG[r + 2][c + 2]) * 0.125f;
            float It = I2w - sG[r + 1][c + 1];
            float vm = (interior || (gy >= 0 && gy < H && gx >= 0 && gx < W)) ? 1.0f : 0.0f;
            Ix *= vm; Iy *= vm; It *= vm;
            sP[0][r][c] = Ix * Ix;
            sP[1][r][c] = Iy * Iy;
            sP[2][r][c] = Ix * Iy;
            sP[3][r][c] = Ix * It;
            sP[4][r][c] = Iy * It;
        }
    }
    __syncthreads();

    // phase 3: horizontal 5-sums
    for (int i = tid; i < 5 * PR * 16; i += 256) {
        int x = i % 16;
        int tt = i / 16;
        int r = tt % PR;
        int ch = tt / PR;
        const float* row = &sP[ch][r][x];
        sH[ch][r][x] = row[0] + row[1] + row[2] + row[3] + row[4];
    }
    __syncthreads();

    // phase 4: vertical 5-sums + solve + flow update
    float Sxx = 0.f, Syy = 0.f, Sxy = 0.f, Sxt = 0.f, Syt = 0.f;
#pragma unroll
    for (int dy = 0; dy < 5; ++dy) {
        Sxx += sH[0][ly + dy][lx];
        Syy += sH[1][ly + dy][lx];
        Sxy += sH[2][ly + dy][lx];
        Sxt += sH[3][ly + dy][lx];
        Syt += sH[4][ly + dy][lx];
    }
    float inv = 1.0f / (Sxx * Syy - Sxy * Sxy + 1e-6f);
    float du = (-Syy * Sxt + Sxy * Syt) * inv;
    float dv = (Sxy * Sxt - Sxx * Syt) * inv;
    int gy = ty0 + ly, gx = tx0 + lx;
    float su = 0.0f, sv = 0.0f;
    if (MODE == 1) {
        float sy = (float)gy * scale, sx = (float)gx * scale;
        int y0 = min(max((int)sy, 0), Hs - 2);
        int x0 = min(max((int)sx, 0), Ws - 2);
        float wyf = sy - (float)y0, wxf = sx - (float)x0;
        int ry = y0 - yA, rx = x0 - xA;
        float ut = sFU[ry][rx] * (1.0f - wyf) + sFU[ry + 1][rx] * wyf;
        float ub = sFU[ry][rx + 1] * (1.0f - wyf) + sFU[ry + 1][rx + 1] * wyf;
        float vt = sFV[ry][rx] * (1.0f - wyf) + sFV[ry + 1][rx] * wyf;
        float vb = sFV[ry][rx + 1] * (1.0f - wyf) + sFV[ry + 1][rx + 1] * wyf;
        su = 2.0f * (ut * (1.0f - wxf) + ub * wxf);
        sv = 2.0f * (vt * (1.0f - wxf) + vb * wxf);
    }
    float* FOU = fout + (size_t)b * 2 * H * W;
    FOU[gy * W + gx] = su + du;
    FOU[H * W + gy * W + gx] = sv + dv;
}

extern "C" void kernel_launch(void* const* d_in, const int* in_sizes, int n_in,
                              void* d_out, int out_size, void* d_ws, size_t ws_size,
                              hipStream_t stream) {
    const float* img1 = (const float*)d_in[0];
    const float* img2 = (const float*)d_in[1];
    float* out = (float*)d_out;
    float* ws = (float*)d_ws;

    const int Hl[4] = {512, 256, 128, 64};
    size_t goff[4];
    size_t tot = 0;
    for (int l = 0; l < 4; ++l) {
        goff[l] = tot;
        tot += (size_t)NB * Hl[l] * Hl[l];
    }
    float* p1 = ws;            // gray pyramid img1
    float* p2 = ws + tot;      // gray pyramid img2
    float* f64 = p2 + tot;
    float* f128 = f64 + (size_t)NB * 2 * 64 * 64;
    float* f256 = f128 + (size_t)NB * 2 * 128 * 128;

    {
        int n = NB * 256 * 256;
        gray_pool_kernel<<<(n + 255) / 256, 256, 0, stream>>>(
            img1, img2, p1 + goff[0], p2 + goff[0], p1 + goff[1], p2 + goff[1]);
    }
    {
        int n = 2 * NB * 64 * 64;
        down2_kernel<<<(n + 255) / 256, 256, 0, stream>>>(
            p1 + goff[1], p2 + goff[1], p1 + goff[2], p2 + goff[2], p1 + goff[3], p2 + goff[3]);
    }
    {
        int nb = NB * (64 / TS) * (64 / TS);
        lk_kernel<0><<<nb, 256, 0, stream>>>(p1 + goff[3], p2 + goff[3], nullptr, f64, 64, 64);
    }
    {
        int nb = NB * (128 / TS) * (128 / TS);
        lk_kernel<1><<<nb, 256, 0, stream>>>(p1 + goff[2], p2 + goff[2], f64, f128, 128, 128);
    }
    {
        int nb = NB * (256 / TS) * (256 / TS);
        lk_kernel<1><<<nb, 256, 0, stream>>>(p1 + goff[1], p2 + goff[1], f128, f256, 256, 256);
    }
    {
        int nb = NB * (512 / TS) * (512 / TS);
        lk_kernel<1><<<nb, 256, 0, stream>>>(p1 + goff[0], p2 + goff[0], f256, out, 512, 512);
    }
}

// Round 8
// 70.531 us; speedup vs baseline: 1.1334x; 1.1334x over previous
//
#include <hip/hip_runtime.h>

#define NB 8
#define TS 16
#define PR 20   // product region (tile + 2 halo each side)
#define GR 22   // g1 region (tile + 3 halo each side)
#define SW 24   // padded LDS row stride
#define SFW 12  // coarse-flow staging window (covers any 20px target span)

typedef float f2 __attribute__((ext_vector_type(2)));

// Fused: channel-mean gray of both 512x512 images + 2x2 avg-pool to level 1.
__global__ void gray_pool_kernel(const float* __restrict__ img1, const float* __restrict__ img2,
                                 float* __restrict__ g0a, float* __restrict__ g0b,
                                 float* __restrict__ g1a, float* __restrict__ g1b) {
    const int W = 512, HW = 512 * 512, Wq = 256, HWq = 256 * 256;
    int i = blockIdx.x * blockDim.x + threadIdx.x;
    if (i >= NB * HWq) return;
    int qx = i % Wq;
    int qy = (i / Wq) % Wq;
    int b = i / HWq;
    size_t base = (size_t)b * 3 * HW + (size_t)(2 * qy) * W + 2 * qx;
    const float third = 1.0f / 3.0f;

    f2 a0c0 = __builtin_nontemporal_load((const f2*)(img1 + base));
    f2 a1c0 = __builtin_nontemporal_load((const f2*)(img1 + base + W));
    f2 a0c1 = __builtin_nontemporal_load((const f2*)(img1 + base + HW));
    f2 a1c1 = __builtin_nontemporal_load((const f2*)(img1 + base + HW + W));
    f2 a0c2 = __builtin_nontemporal_load((const f2*)(img1 + base + 2 * HW));
    f2 a1c2 = __builtin_nontemporal_load((const f2*)(img1 + base + 2 * HW + W));
    float p00 = (a0c0.x + a0c1.x + a0c2.x) * third;
    float p01 = (a0c0.y + a0c1.y + a0c2.y) * third;
    float p10 = (a1c0.x + a1c1.x + a1c2.x) * third;
    float p11 = (a1c0.y + a1c1.y + a1c2.y) * third;
    size_t gbase = (size_t)b * HW + (size_t)(2 * qy) * W + 2 * qx;
    *(f2*)(g0a + gbase) = (f2){p00, p01};
    *(f2*)(g0a + gbase + W) = (f2){p10, p11};
    g1a[(size_t)b * HWq + qy * Wq + qx] = (p00 + p01 + p10 + p11) * 0.25f;

    f2 b0c0 = __builtin_nontemporal_load((const f2*)(img2 + base));
    f2 b1c0 = __builtin_nontemporal_load((const f2*)(img2 + base + W));
    f2 b0c1 = __builtin_nontemporal_load((const f2*)(img2 + base + HW));
    f2 b1c1 = __builtin_nontemporal_load((const f2*)(img2 + base + HW + W));
    f2 b0c2 = __builtin_nontemporal_load((const f2*)(img2 + base + 2 * HW));
    f2 b1c2 = __builtin_nontemporal_load((const f2*)(img2 + base + 2 * HW + W));
    float q00 = (b0c0.x + b0c1.x + b0c2.x) * third;
    float q01 = (b0c0.y + b0c1.y + b0c2.y) * third;
    float q10 = (b1c0.x + b1c1.x + b1c2.x) * third;
    float q11 = (b1c0.y + b1c1.y + b1c2.y) * third;
    *(f2*)(g0b + gbase) = (f2){q00, q01};
    *(f2*)(g0b + gbase + W) = (f2){q10, q11};
    g1b[(size_t)b * HWq + qy * Wq + qx] = (q00 + q01 + q10 + q11) * 0.25f;
}

// Fused pyramid levels 2+3 for both images.
__global__ void down2_kernel(const float* __restrict__ l1a, const float* __restrict__ l1b,
                             float* __restrict__ l2a, float* __restrict__ l2b,
                             float* __restrict__ l3a, float* __restrict__ l3b) {
    const int W3 = 64, W2 = 128, W1 = 256;
    int i = blockIdx.x * blockDim.x + threadIdx.x;
    int total = 2 * NB * W3 * W3;
    if (i >= total) return;
    int x3 = i % W3;
    int y3 = (i / W3) % W3;
    int b = (i / (W3 * W3)) % NB;
    int j = i / (NB * W3 * W3);
    const float* l1 = (j ? l1b : l1a) + (size_t)b * W1 * W1;
    float* l2 = (j ? l2b : l2a) + (size_t)b * W2 * W2;
    float* l3 = (j ? l3b : l3a) + (size_t)b * W3 * W3;
    float4 r0 = *(const float4*)(l1 + (size_t)(4 * y3 + 0) * W1 + 4 * x3);
    float4 r1 = *(const float4*)(l1 + (size_t)(4 * y3 + 1) * W1 + 4 * x3);
    float4 r2 = *(const float4*)(l1 + (size_t)(4 * y3 + 2) * W1 + 4 * x3);
    float4 r3 = *(const float4*)(l1 + (size_t)(4 * y3 + 3) * W1 + 4 * x3);
    float a00 = (r0.x + r0.y + r1.x + r1.y) * 0.25f;
    float a01 = (r0.z + r0.w + r1.z + r1.w) * 0.25f;
    float a10 = (r2.x + r2.y + r3.x + r3.y) * 0.25f;
    float a11 = (r2.z + r2.w + r3.z + r3.w) * 0.25f;
    *(f2*)(l2 + (size_t)(2 * y3) * W2 + 2 * x3) = (f2){a00, a01};
    *(f2*)(l2 + (size_t)(2 * y3 + 1) * W2 + 2 * x3) = (f2){a10, a11};
    l3[y3 * W3 + x3] = (a00 + a01 + a10 + a11) * 0.25f;
}

// 16x16-tile LK, compile-time H/W. Flow upsample from LDS-staged coarse
// window; warp via global clamped gathers with a per-pixel interior fast path.
template <int MODE, int H, int W>
__global__ __launch_bounds__(256) void lk_kernel(
    const float* __restrict__ g1, const float* __restrict__ g2,
    const float* __restrict__ fin, float* __restrict__ fout) {
    __shared__ float sG[GR][SW];
    __shared__ float sU[PR][SW], sV[PR][SW];
    __shared__ float sP[5][PR][SW];
    __shared__ float sH[5][PR][16];
    __shared__ float sFU[SFW][SFW + 1], sFV[SFW][SFW + 1];

    constexpr int nbx = W / TS;
    constexpr int Hs = H / 2, Ws = W / 2;
    constexpr float scale = (float)(Hs - 1) / (float)(H - 1);

    int b = blockIdx.x % NB;
    int t = blockIdx.x / NB;
    int ty0 = (t / nbx) * TS, tx0 = (t % nbx) * TS;
    int tid = threadIdx.x;
    int lx = tid % TS, ly = tid / TS;

    const float* G1 = g1 + (size_t)b * H * W;
    const float* G2 = g2 + (size_t)b * H * W;
    bool interior = (ty0 >= 3) && (ty0 + TS + 3 <= H) && (tx0 >= 3) && (tx0 + TS + 3 <= W);

    int yA = 0, xA = 0;
    if (MODE == 1) {
        yA = min(max((int)((float)max(ty0 - 2, 0) * scale), 0), Hs - 2);
        xA = min(max((int)((float)max(tx0 - 2, 0) * scale), 0), Ws - 2);
        const float* FU = fin + (size_t)b * 2 * Hs * Ws;
        const float* FV = FU + Hs * Ws;
        for (int i = tid; i < 2 * SFW * SFW; i += 256) {
            int ch = i / (SFW * SFW);
            int rem = i % (SFW * SFW);
            int r = rem / SFW, c = rem % SFW;
            int ys = min(yA + r, Hs - 1), xs = min(xA + c, Ws - 1);
            float v = (ch ? FV : FU)[(size_t)ys * Ws + xs];
            if (ch) sFV[r][c] = v; else sFU[r][c] = v;
        }
    }
    // stage G1 tile (halo 3, zero-padded)
    if (interior) {
        for (int i = tid; i < GR * GR; i += 256) {
            int r = i / GR, c = i % GR;
            sG[r][c] = G1[(ty0 - 3 + r) * W + (tx0 - 3 + c)];
        }
    } else {
        for (int i = tid; i < GR * GR; i += 256) {
            int r = i / GR, c = i % GR;
            int gy = ty0 - 3 + r, gx = tx0 - 3 + c;
            float v = 0.0f;
            if (gy >= 0 && gy < H && gx >= 0 && gx < W) v = G1[gy * W + gx];
            sG[r][c] = v;
        }
    }
    __syncthreads();

    // phase 2: flow interp + Sobel + warp (fast/slow path) + products
#pragma unroll
    for (int it = 0; it < 2; ++it) {
        int i = tid + it * 256;
        if (i < PR * PR) {
            int r = i / PR, c = i % PR;
            int gy = ty0 - 2 + r, gx = tx0 - 2 + c;
            float su = 0.0f, sv = 0.0f;
            if (MODE == 1) {
                float sy = (float)gy * scale, sx = (float)gx * scale;
                int y0 = min(max((int)sy, 0), Hs - 2);
                int x0 = min(max((int)sx, 0), Ws - 2);
                float wyf = sy - (float)y0, wxf = sx - (float)x0;
                int ry = y0 - yA, rx = x0 - xA;
                float ut = sFU[ry][rx] * (1.0f - wyf) + sFU[ry + 1][rx] * wyf;
                float ub = sFU[ry][rx + 1] * (1.0f - wyf) + sFU[ry + 1][rx + 1] * wyf;
                float vt = sFV[ry][rx] * (1.0f - wyf) + sFV[ry + 1][rx] * wyf;
                float vb = sFV[ry][rx + 1] * (1.0f - wyf) + sFV[ry + 1][rx + 1] * wyf;
                su = 2.0f * (ut * (1.0f - wxf) + ub * wxf);
                sv = 2.0f * (vt * (1.0f - wxf) + vb * wxf);
            }
            sU[r][c] = su;
            sV[r][c] = sv;

            float xx = (float)gx + su, yy = (float)gy + sv;
            float x0f = floorf(xx), y0f = floorf(yy);
            float wx = xx - x0f, wy = yy - y0f;
            int xi = (int)x0f, yi = (int)y0f;
            float I2w;
            bool safe = (xi >= 0) && (xi <= W - 2) && (yi >= 0) && (yi <= H - 2);
            if (__builtin_expect(safe, 1)) {
                // all 4 corners in-bounds, all masks 1
                const float* p = G2 + yi * W + xi;
                float v00 = p[0], v01 = p[1], v10 = p[W], v11 = p[W + 1];
                float omwx = 1.0f - wx, omwy = 1.0f - wy;
                I2w = (v00 * omwx + v01 * wx) * omwy + (v10 * omwx + v11 * wx) * wy;
            } else {
                int xc0 = min(max(xi, 0), W - 1), xc1 = min(max(xi + 1, 0), W - 1);
                int yc0 = min(max(yi, 0), H - 1), yc1 = min(max(yi + 1, 0), H - 1);
                float v00 = G2[yc0 * W + xc0];
                float v01 = G2[yc0 * W + xc1];
                float v10 = G2[yc1 * W + xc0];
                float v11 = G2[yc1 * W + xc1];
                float mx0 = (x0f >= 0.0f && x0f <= (float)(W - 1)) ? 1.0f : 0.0f;
                float mx1 = (x0f + 1.0f >= 0.0f && x0f + 1.0f <= (float)(W - 1)) ? 1.0f : 0.0f;
                float my0 = (y0f >= 0.0f && y0f <= (float)(H - 1)) ? 1.0f : 0.0f;
                float my1 = (y0f + 1.0f >= 0.0f && y0f + 1.0f <= (float)(H - 1)) ? 1.0f : 0.0f;
                I2w = v00 * ((1.0f - wx) * (1.0f - wy) * mx0 * my0)
                    + v01 * (wx * (1.0f - wy) * mx1 * my0)
                    + v10 * ((1.0f - wx) * wy * mx0 * my1)
                    + v11 * (wx * wy * mx1 * my1);
            }
            float Ix = (-sG[r][c] + sG[r][c + 2]
                        - 2.0f * sG[r + 1][c] + 2.0f * sG[r + 1][c + 2]
                        - sG[r + 2][c] + sG[r + 2][c + 2]) * 0.125f;
            float Iy = (-sG[r][c] - 2.0f * sG[r][c + 1] - sG[r][c + 2]
                        + sG[r + 2][c] + 2.0f * sG[r + 2][c + 1] + sG[r + 2][c + 2]) * 0.125f;
            float It = I2w - sG[r + 1][c + 1];
            if (!interior) {
                float vm = (gy >= 0 && gy < H && gx >= 0 && gx < W) ? 1.0f : 0.0f;
                Ix *= vm; Iy *= vm; It *= vm;
            }
            sP[0][r][c] = Ix * Ix;
            sP[1][r][c] = Iy * Iy;
            sP[2][r][c] = Ix * Iy;
            sP[3][r][c] = Ix * It;
            sP[4][r][c] = Iy * It;
        }
    }
    __syncthreads();

    // phase 3: horizontal 5-sums
    for (int i = tid; i < 5 * PR * 16; i += 256) {
        int x = i % 16;
        int tt = i / 16;
        int r = tt % PR;
        int ch = tt / PR;
        const float* row = &sP[ch][r][x];
        sH[ch][r][x] = row[0] + row[1] + row[2] + row[3] + row[4];
    }
    __syncthreads();

    // phase 4: vertical 5-sums + solve + flow update
    float Sxx = 0.f, Syy = 0.f, Sxy = 0.f, Sxt = 0.f, Syt = 0.f;
#pragma unroll
    for (int dy = 0; dy < 5; ++dy) {
        Sxx += sH[0][ly + dy][lx];
        Syy += sH[1][ly + dy][lx];
        Sxy += sH[2][ly + dy][lx];
        Sxt += sH[3][ly + dy][lx];
        Syt += sH[4][ly + dy][lx];
    }
    float inv = 1.0f / (Sxx * Syy - Sxy * Sxy + 1e-6f);
    float du = (-Syy * Sxt + Sxy * Syt) * inv;
    float dv = (Sxy * Sxt - Sxx * Syt) * inv;
    int gy = ty0 + ly, gx = tx0 + lx;
    float* FOU = fout + (size_t)b * 2 * H * W;
    FOU[gy * W + gx] = sU[ly + 2][lx + 2] + du;
    FOU[H * W + gy * W + gx] = sV[ly + 2][lx + 2] + dv;
}

extern "C" void kernel_launch(void* const* d_in, const int* in_sizes, int n_in,
                              void* d_out, int out_size, void* d_ws, size_t ws_size,
                              hipStream_t stream) {
    const float* img1 = (const float*)d_in[0];
    const float* img2 = (const float*)d_in[1];
    float* out = (float*)d_out;
    float* ws = (float*)d_ws;

    const int Hl[4] = {512, 256, 128, 64};
    size_t goff[4];
    size_t tot = 0;
    for (int l = 0; l < 4; ++l) {
        goff[l] = tot;
        tot += (size_t)NB * Hl[l] * Hl[l];
    }
    float* p1 = ws;            // gray pyramid img1
    float* p2 = ws + tot;      // gray pyramid img2
    float* f64 = p2 + tot;
    float* f128 = f64 + (size_t)NB * 2 * 64 * 64;
    float* f256 = f128 + (size_t)NB * 2 * 128 * 128;

    {
        int n = NB * 256 * 256;
        gray_pool_kernel<<<(n + 255) / 256, 256, 0, stream>>>(
            img1, img2, p1 + goff[0], p2 + goff[0], p1 + goff[1], p2 + goff[1]);
    }
    {
        int n = 2 * NB * 64 * 64;
        down2_kernel<<<(n + 255) / 256, 256, 0, stream>>>(
            p1 + goff[1], p2 + goff[1], p1 + goff[2], p2 + goff[2], p1 + goff[3], p2 + goff[3]);
    }
    {
        int nb = NB * (64 / TS) * (64 / TS);
        lk_kernel<0, 64, 64><<<nb, 256, 0, stream>>>(p1 + goff[3], p2 + goff[3], nullptr, f64);
    }
    {
        int nb = NB * (128 / TS) * (128 / TS);
        lk_kernel<1, 128, 128><<<nb, 256, 0, stream>>>(p1 + goff[2], p2 + goff[2], f64, f128);
    }
    {
        int nb = NB * (256 / TS) * (256 / TS);
        lk_kernel<1, 256, 256><<<nb, 256, 0, stream>>>(p1 + goff[1], p2 + goff[1], f128, f256);
    }
    {
        int nb = NB * (512 / TS) * (512 / TS);
        lk_kernel<1, 512, 512><<<nb, 256, 0, stream>>>(p1 + goff[0], p2 + goff[0], f256, out);
    }
}